// Round 10
// baseline (324.304 us; speedup 1.0000x reference)
//
#include <hip/hip_runtime.h>

// Shapes fixed by setup_inputs: B=8, C=64, H=W=64, CTX=64, SF=2
// f1 = prelu(conv3x3(ctx)+b1)   : [8][64][64][64]   (ws)
// f2 = prelu(conv3x3(f1)+b2)    : [8][32][64][64]   (ws)
// out = fused 1x1conv(kp) + softmax(9 taps) + upsample (mask never materialized)
// R10: convs go global-direct (no LDS, no barriers — inputs are L2/L3-resident;
// the 50KB LDS staging + barrier was pure serialization at 2 blocks/CU).
// Upsample byte-identical to R9 (passed, 125 us).

// ---------------- conv 3x3 + bias + prelu, global-direct ----------------
// grid(2, 64, 8) = (s, h, b); 256 threads = 4 waves: lane w = t&63, wave cg.
// Wave computes CPT channels starting at (s*4+cg)*CPT. No LDS, no syncs.
template <int CIN, int COUT, int CPT>
__global__ __launch_bounds__(256) void k_conv3x3g(
    const float* __restrict__ x,      // [B][CIN][64][64]
    const float* __restrict__ wgt,    // [COUT][CIN][3][3]
    const float* __restrict__ bias,   // [COUT]
    const float* __restrict__ alpha,  // [COUT]
    float* __restrict__ y)            // [B][COUT][64][64]
{
    const int s = blockIdx.x;
    const int h = blockIdx.y;
    const int b = blockIdx.z;
    const int t = threadIdx.x;
    const int w  = t & 63;
    const int cg = __builtin_amdgcn_readfirstlane(t >> 6);  // wave-uniform 0..3
    const int co0 = (s * 4 + cg) * CPT;

    float acc[CPT];
#pragma unroll
    for (int i = 0; i < CPT; ++i) acc[i] = bias[co0 + i];

    const bool w0 = (w > 0), w1 = (w < 63);
    const float* xp = x + ((size_t)(b * CIN) * 64 + h) * 64 + w;  // ci advances by 4096

    for (int ci = 0; ci < CIN; ++ci) {
        float v[3][3];
#pragma unroll
        for (int r = 0; r < 3; ++r) {
            const int hh = h + r - 1;              // wave-uniform bounds check
            if (hh >= 0 && hh < 64) {
                const float* p = xp + (r - 1) * 64;
                v[r][0] = w0 ? p[-1] : 0.f;
                v[r][1] = p[0];
                v[r][2] = w1 ? p[1] : 0.f;
            } else {
                v[r][0] = 0.f; v[r][1] = 0.f; v[r][2] = 0.f;
            }
        }
#pragma unroll
        for (int co = 0; co < CPT; ++co) {
            const float* wp = &wgt[((co0 + co) * CIN + ci) * 9];
            float a = acc[co];
            a = fmaf(wp[0], v[0][0], a);
            a = fmaf(wp[1], v[0][1], a);
            a = fmaf(wp[2], v[0][2], a);
            a = fmaf(wp[3], v[1][0], a);
            a = fmaf(wp[4], v[1][1], a);
            a = fmaf(wp[5], v[1][2], a);
            a = fmaf(wp[6], v[2][0], a);
            a = fmaf(wp[7], v[2][1], a);
            a = fmaf(wp[8], v[2][2], a);
            acc[co] = a;
        }
        xp += 4096;
    }

#pragma unroll
    for (int co = 0; co < CPT; ++co) {
        float a  = acc[co];
        float al = alpha[co0 + co];
        float o  = (a > 0.f) ? a : al * a;
        y[((b * COUT + co0 + co) * 64 + h) * 64 + w] = o;
    }
}

// ---------------- fused 1x1-conv + softmax + upsample (R9, unchanged) ------
// grid(2, 64, 8) = (cq, w, b); 512 threads = 8 waves: lane h = t&63, wave cg.
__global__ __launch_bounds__(512, 4) void k_upsample(
    const float* __restrict__ f2,    // [B][32][64][64]
    const float* __restrict__ kpw,   // [2304][32]
    const float* __restrict__ kpb,   // [2304]
    const float* __restrict__ xlow,  // [B][64][64][64]
    float* __restrict__ out)         // [B][64][128][128]
{
    const int cq = blockIdx.x;
    const int w  = blockIdx.y;
    const int b  = blockIdx.z;
    __shared__ float F[32][64];      // f2[ci][h] for this (b, w) column
    __shared__ float Xl[32][3][64];  // xlow[cq*32+ci][w-1+dx clamped][h]
    const int t = threadIdx.x;

    for (int idx = t; idx < 32 * 64; idx += 512) {
        int ci = idx >> 6, h = idx & 63;
        F[ci][h] = f2[((b * 32 + ci) * 64 + h) * 64 + w];
    }
    for (int idx = t; idx < 32 * 3 * 64; idx += 512) {
        int h = idx & 63, dx = (idx >> 6) % 3, ci = idx / 192;
        int ww = min(max(w + dx - 1, 0), 63);
        Xl[ci][dx][h] = xlow[((b * 64 + cq * 32 + ci) * 64 + h) * 64 + ww];
    }
    __syncthreads();

    const int h  = t & 63;
    const int cg = __builtin_amdgcn_readfirstlane(t >> 6);  // wave-uniform 0..7

    float fu[32];
#pragma unroll
    for (int ci = 0; ci < 32; ++ci) fu[ci] = F[ci][h];

    const int hm = max(h - 1, 0), hp = min(h + 1, 63);

    for (int cc = 0; cc < 4; ++cc) {
        const int c  = cq * 32 + cg * 4 + cc;   // global channel (wave-uniform)
        const int cl = cg * 4 + cc;             // local channel for Xl
        const float4* wp4 = (const float4*)(kpw + c * 36 * 32);
        const float*  bp  = kpb + c * 36;

#pragma unroll
        for (int q = 0; q < 2; ++q) {
            float o2[2];
#pragma unroll
            for (int p = 0; p < 2; ++p) {
                const int pq = p * 2 + q;
                float acc[9];
#pragma unroll
                for (int k = 0; k < 9; ++k) acc[k] = bp[k * 4 + pq];
#pragma unroll
                for (int ci4 = 0; ci4 < 8; ++ci4) {
                    float f0 = fu[ci4 * 4 + 0], f1 = fu[ci4 * 4 + 1];
                    float f2v = fu[ci4 * 4 + 2], f3 = fu[ci4 * 4 + 3];
#pragma unroll
                    for (int k = 0; k < 9; ++k) {
                        float4 wv = wp4[(k * 4 + pq) * 8 + ci4];
                        acc[k] = fmaf(wv.x, f0,
                                 fmaf(wv.y, f1,
                                 fmaf(wv.z, f2v,
                                 fmaf(wv.w, f3, acc[k]))));
                    }
                }
                float m = acc[0];
#pragma unroll
                for (int k = 1; k < 9; ++k) m = fmaxf(m, acc[k]);
                float s = 0.f, ov = 0.f;
#pragma unroll
                for (int k = 0; k < 9; ++k) {
                    const int dy = k / 3, dx = k % 3;
                    const int hh = (dy == 0) ? hm : (dy == 1 ? h : hp);
                    float e = __expf(acc[k] - m);
                    s += e;
                    ov = fmaf(e, Xl[cl][dx][hh], ov);
                }
                o2[p] = ov / s;
            }
            // out[b][c][2w+q][2h+p]; p contiguous -> float2, lanes h -> coalesced
            *(float2*)&out[((b * 64 + c) * 128 + (2 * w + q)) * 128 + 2 * h] =
                make_float2(o2[0], o2[1]);
        }
    }
}

extern "C" void kernel_launch(void* const* d_in, const int* in_sizes, int n_in,
                              void* d_out, int out_size, void* d_ws, size_t ws_size,
                              hipStream_t stream) {
    (void)in_sizes; (void)n_in; (void)out_size; (void)ws_size;
    const float* x_low = (const float*)d_in[0];
    const float* ctx   = (const float*)d_in[1];
    const float* c1_w  = (const float*)d_in[2];
    const float* c1_b  = (const float*)d_in[3];
    const float* p1_a  = (const float*)d_in[4];
    const float* c2_w  = (const float*)d_in[5];
    const float* c2_b  = (const float*)d_in[6];
    const float* p2_a  = (const float*)d_in[7];
    const float* kp_w  = (const float*)d_in[8];
    const float* kp_b  = (const float*)d_in[9];
    float* out = (float*)d_out;

    float* f1 = (float*)d_ws;                  // 8*64*64*64 floats = 8 MB
    float* f2 = f1 + 8 * 64 * 64 * 64;         // 8*32*64*64 floats = 4 MB

    k_conv3x3g<64, 64, 8><<<dim3(2, 64, 8), 256, 0, stream>>>(ctx, c1_w, c1_b, p1_a, f1);
    k_conv3x3g<64, 32, 4><<<dim3(2, 64, 8), 256, 0, stream>>>(f1, c2_w, c2_b, p2_a, f2);
    k_upsample<<<dim3(2, 64, 8), 512, 0, stream>>>(f2, kp_w, kp_b, x_low, out);
}